// Round 9
// baseline (528.328 us; speedup 1.0000x reference)
//
#include <hip/hip_runtime.h>
#include <hip/hip_fp16.h>
#include <stdint.h>

static constexpr int Bc = 16, Cc = 256, Hc = 56, Wc = 56, Gc = 4;
static constexpr int HWc = Hc * Wc;
static constexpr float EPSc = 1e-5f;
static constexpr int ROWB = 72;          // padded w' positions per abytes row
static constexpr int COL0 = 8;           // [8 zero | 56 data | 8 zero]
static constexpr int ROWBYTES = ROWB * 64;  // 4608 B per (b,g,h) row
static constexpr int ZBYTES = 8192;      // zero row area (max read 4928 B)

typedef int i32x4 __attribute__((ext_vector_type(4)));

// ---------------------------------------------------------------------------
// Workspace:
//   ws + 0        : 8192 B zero area (zero "row"; conv reads <= 4928 B)
//   ws + 8192     : abytes [16][4][56][72][64] i8 = 16,515,072 B
//                   (sign bytes +-1; w' pads are 0 -> zero-padding is exact)
//   ws + 16523264 : wbytes [3][4][9][64 o][64 ci] i8 = 442,368 B
//   ws + 16965632 : scales [768] f32
// Overflow note: A-frag reads may run <=320 B past a row's end; they land in
// the next row's leading zero pad (512 B) or, for the very last row, in
// wbytes (allocated; affects only w>=56 garbage lanes, never stored).
// ---------------------------------------------------------------------------

static constexpr int SBS2 = 132;  // sign-byte LDS row stride (128 ch + pad)

__global__ __launch_bounds__(256) void k_prep(
    const float* __restrict__ w, const float* __restrict__ x,
    const float* __restrict__ bias, uint8_t* __restrict__ wbytes,
    float* __restrict__ scales, uint8_t* __restrict__ abytes,
    uint32_t* __restrict__ zero_area) {
  const int t = threadIdx.x;
  if (blockIdx.x < 192) {
    // ---- weight pack: io = blockIdx*4 + wave; lane = ci ----
    const int io = blockIdx.x * 4 + (t >> 6);
    const int i = io >> 8, o = io & 255;
    const int lane = t & 63;
    const float* wp = w + (size_t)io * 576 + lane * 9;
    float v[9];
    float ssum = 0.f, sabs = 0.f;
#pragma unroll
    for (int k = 0; k < 9; ++k) {
      v[k] = wp[k];
      ssum += v[k];
      sabs += fabsf(v[k]);
    }
#pragma unroll
    for (int off = 32; off > 0; off >>= 1) {
      ssum += __shfl_down(ssum, off);
      sabs += __shfl_down(sabs, off);
    }
    const float mean = __shfl(ssum, 0) * (1.f / 576.f);
    const float scale = __shfl(sabs, 0) * (1.f / 576.f);
    const int g = o >> 6, ol = o & 63;
    uint8_t* dst = wbytes + ((size_t)(i * 4 + g) * 9) * 4096 + ol * 64 + lane;
#pragma unroll
    for (int k = 0; k < 9; ++k)
      dst[k * 4096] = (v[k] > mean) ? (uint8_t)1 : (uint8_t)0xFF;
    if (lane == 0) scales[io] = scale;
  } else if (blockIdx.x == 192) {
    // zero area: 512 x 16 B = 8192 B
    uint4 z;
    z.x = z.y = z.z = z.w = 0u;
    ((uint4*)zero_area)[t] = z;
    ((uint4*)zero_area)[t + 256] = z;
  } else {
    // ---- activation pack: block = (b, h, channel-half). Coalesced float4
    // loads + LDS byte transpose; emit +-1 bytes [w'][ci] (u32 copies).
    __shared__ uint8_t sb[Wc * SBS2];  // [w][c_local], 7392 B
    const int bid = blockIdx.x - 193;
    const int b = bid / 112;
    const int rem = bid - b * 112;
    const int h = rem >> 1, chh = rem & 1;  // chh: channels [chh*128, +128)
    const float* xb = x + ((size_t)(b * Cc + chh * 128)) * HWc + h * Wc;
#pragma unroll
    for (int k = 0; k < 7; ++k) {
      const int idx = k * 256 + t;  // [0, 1792) = 128 c x 14 q
      const int cl = idx / 14, q = idx - cl * 14;
      const float4 v = *(const float4*)(xb + (size_t)cl * HWc + q * 4);
      const float bc = bias[chh * 128 + cl];
      sb[(q * 4 + 0) * SBS2 + cl] = (v.x + bc > 0.f) ? 1 : 0xFF;
      sb[(q * 4 + 1) * SBS2 + cl] = (v.y + bc > 0.f) ? 1 : 0xFF;
      sb[(q * 4 + 2) * SBS2 + cl] = (v.z + bc > 0.f) ? 1 : 0xFF;
      sb[(q * 4 + 3) * SBS2 + cl] = (v.w + bc > 0.f) ? 1 : 0xFF;
    }
    __syncthreads();
    // emit: 2 local groups x 72 w' x 16 dwords = 2304 u32 (9 iters)
    for (int idx = t; idx < 2 * ROWB * 16; idx += 256) {
      const int gl = idx / (ROWB * 16);
      const int r = idx - gl * (ROWB * 16);
      const int wp_ = r >> 4, d4 = r & 15;
      uint32_t word = 0;
      if (wp_ >= COL0 && wp_ < COL0 + Wc)
        word = *(const uint32_t*)(sb + (wp_ - COL0) * SBS2 + gl * 64 + d4 * 4);
      const int g = chh * 2 + gl;
      *(uint32_t*)(abytes + ((size_t)((b * Gc + g) * Hc + h)) * ROWBYTES +
                   wp_ * 64 + d4 * 4) = word;
    }
  }
}

// ---------------------------------------------------------------------------
// One branch for one m0p pass, 16x16x64 i8 MFMA. Fragment footprints are
// CONTIGUOUS 1 KB in the [w'][ci]/[o][ci] layouts (lane l: row l&15,
// K-chunk (l>>4)*16) — fixes r8's strided-16B L1 throughput wall.
// Holds 18 A-frags (2 M-tiles x 9 taps, 72 VGPR); streams B per (n, tap);
// sched_barrier(0) per n-tile bounds in-flight B-loads at 36 VGPR.
// D/C (m89/m91-verified): col = lane&15 = o, row = (lane>>4)*4 + q = w.
// ---------------------------------------------------------------------------
template <int D>
__device__ __forceinline__ void conv_branch(
    const uint8_t* __restrict__ r0, const uint8_t* __restrict__ r1,
    const uint8_t* __restrict__ r2, const uint8_t* __restrict__ wb,
    int m0p, int lr, int kc, const float (&sc)[4], const float (&cc)[4],
    const float (&aa)[4], float (&outf)[2][4][4]) {
  i32x4 A[2][9];
#pragma unroll
  for (int m = 0; m < 2; ++m)
#pragma unroll
    for (int tap = 0; tap < 9; ++tap) {
      const uint8_t* r = (tap < 3) ? r0 : ((tap < 6) ? r1 : r2);
      const int kw = tap % 3 - 1;
      A[m][tap] = *(const i32x4*)(
          r + (COL0 + m0p * 32 + m * 16 + D * kw + lr) * 64 + kc);
    }
#pragma unroll
  for (int n = 0; n < 4; ++n) {
    i32x4 a0 = {0, 0, 0, 0}, a1 = {0, 0, 0, 0};
#pragma unroll
    for (int tap = 0; tap < 9; ++tap) {
      const i32x4 Bf =
          *(const i32x4*)(wb + tap * 4096 + n * 1024 + lr * 64 + kc);
      a0 = __builtin_amdgcn_mfma_i32_16x16x64_i8(A[0][tap], Bf, a0, 0, 0, 0);
      a1 = __builtin_amdgcn_mfma_i32_16x16x64_i8(A[1][tap], Bf, a1, 0, 0, 0);
    }
#pragma unroll
    for (int q = 0; q < 4; ++q) {
      const float y0 = fmaf(sc[n], (float)a0[q], cc[n]);
      outf[0][n][q] += fmaxf(y0, 0.f) + aa[n] * fminf(y0, 0.f);
      const float y1 = fmaf(sc[n], (float)a1[q], cc[n]);
      outf[1][n][q] += fmaxf(y1, 0.f) + aa[n] * fminf(y1, 0.f);
    }
    __builtin_amdgcn_sched_barrier(0);  // bound cross-n load hoisting (VGPR)
  }
}

// ---------------------------------------------------------------------------
// K2: fused conv(3 branches, 16x16x64 i8 MFMA)+bias+RPReLU+sum+LayerNorm.
// Block = (b,h) full row; wave = group g. XCD-chunked bijective swizzle
// (896 = 8*112) keeps each XCD's abytes slice L2-resident (r8: FETCH 11 MB).
// ---------------------------------------------------------------------------
static constexpr int TS = 60;  // out_tile stride (halfs)

__global__ __launch_bounds__(256, 2) void k_conv_ln(
    const uint8_t* __restrict__ abytes, const uint8_t* __restrict__ zb,
    const uint8_t* __restrict__ wbytes, const float* __restrict__ scales,
    const float* __restrict__ cb, const float* __restrict__ mv1,
    const float* __restrict__ al, const float* __restrict__ mv2,
    const float* __restrict__ gamma, const float* __restrict__ beta,
    float* __restrict__ out) {
  __shared__ __half out_tile[Cc * TS];
  __shared__ float redu[4][Wc], redq[4][Wc];
  __shared__ float mstat[Wc], rstat[Wc];

  const int bid0 = blockIdx.x;                     // hw id (round-robin XCD)
  const int bid = (bid0 & 7) * 112 + (bid0 >> 3);  // b*56 + h, XCD-chunked
  const int b = bid / Hc, h = bid % Hc;
  const int t = threadIdx.x;
  const int gu = __builtin_amdgcn_readfirstlane(t >> 6);  // group
  const int lane = t & 63;
  const int lr = lane & 15;           // row (w) / col (o) within 16-tile
  const int kc = (lane >> 4) * 16;    // K-chunk byte offset

  const uint8_t* ab_g = abytes + (size_t)((b * Gc + gu) * Hc) * ROWBYTES;
  const uint8_t* r1m = (h - 1 >= 0) ? ab_g + (size_t)(h - 1) * ROWBYTES : zb;
  const uint8_t* rmd = ab_g + (size_t)h * ROWBYTES;
  const uint8_t* r1p = (h + 1 < Hc) ? ab_g + (size_t)(h + 1) * ROWBYTES : zb;
  const uint8_t* r3m = (h - 3 >= 0) ? ab_g + (size_t)(h - 3) * ROWBYTES : zb;
  const uint8_t* r3p = (h + 3 < Hc) ? ab_g + (size_t)(h + 3) * ROWBYTES : zb;
  const uint8_t* r5m = (h - 5 >= 0) ? ab_g + (size_t)(h - 5) * ROWBYTES : zb;
  const uint8_t* r5p = (h + 5 < Hc) ? ab_g + (size_t)(h + 5) * ROWBYTES : zb;

  const uint8_t* wb0 = wbytes + (size_t)(0 * Gc + gu) * 9 * 4096;
  const uint8_t* wb1 = wbytes + (size_t)(1 * Gc + gu) * 9 * 4096;
  const uint8_t* wb2 = wbytes + (size_t)(2 * Gc + gu) * 9 * 4096;

  // per-(branch, n-tile) epilogue params; all uses statically indexed
  float sc[3][4], cc[3][4], aa[3][4], m2[4];
#pragma unroll
  for (int n = 0; n < 4; ++n) {
    const int o = gu * 64 + n * 16 + lr;
    m2[n] = mv2[o] + mv2[256 + o] + mv2[512 + o];
#pragma unroll
    for (int br = 0; br < 3; ++br) {
      sc[br][n] = scales[br * 256 + o];
      cc[br][n] = cb[br * 256 + o] - mv1[br * 256 + o];
      aa[br][n] = al[br * 256 + o];
    }
  }

#pragma unroll 1
  for (int m0p = 0; m0p < 2; ++m0p) {  // w 32-halves (2 x 16-row M-tiles)
    float outf[2][4][4];  // [m][n][q], static-indexed
#pragma unroll
    for (int m = 0; m < 2; ++m)
#pragma unroll
      for (int n = 0; n < 4; ++n)
#pragma unroll
        for (int q = 0; q < 4; ++q) outf[m][n][q] = m2[n];

    conv_branch<1>(r1m, rmd, r1p, wb0, m0p, lr, kc, sc[0], cc[0], aa[0], outf);
    conv_branch<3>(r3m, rmd, r3p, wb1, m0p, lr, kc, sc[1], cc[1], aa[1], outf);
    conv_branch<5>(r5m, rmd, r5p, wb2, m0p, lr, kc, sc[2], cc[2], aa[2], outf);

    // store: o = gu*64 + n*16 + lr (col), w = m0p*32 + m*16 + (lane>>4)*4 + q
    const int wq = (lane >> 4) * 4;
#pragma unroll
    for (int m = 0; m < 2; ++m) {
      const int w0 = m0p * 32 + m * 16 + wq;
#pragma unroll
      for (int n = 0; n < 4; ++n) {
        const int o = gu * 64 + n * 16 + lr;
#pragma unroll
        for (int q = 0; q < 4; ++q) {
          const int wl = w0 + q;
          if (wl < Wc) out_tile[o * TS + wl] = __float2half(outf[m][n][q]);
        }
      }
    }
  }
  __syncthreads();

  // ---- LN stats (per output column over 256 channels) ----
  if (t < 4 * Wc) {
    const int ww = t % Wc;
    const int cq = t / Wc;
    float s = 0.f, sq = 0.f;
#pragma unroll 4
    for (int c = cq * 64; c < cq * 64 + 64; ++c) {
      const float v = __half2float(out_tile[c * TS + ww]);
      s += v;
      sq = fmaf(v, v, sq);
    }
    redu[cq][ww] = s;
    redq[cq][ww] = sq;
  }
  __syncthreads();
  if (t < Wc) {
    const float s = redu[0][t] + redu[1][t] + redu[2][t] + redu[3][t];
    const float sq = redq[0][t] + redq[1][t] + redq[2][t] + redq[3][t];
    const float mean = s * (1.f / 256.f);
    const float var = sq * (1.f / 256.f) - mean * mean;
    mstat[t] = mean;
    rstat[t] = rsqrtf(var + EPSc);
  }
  __syncthreads();

  // ---- normalize + coalesced store ----
  float* base = out + ((size_t)b * Cc * Hc + h) * Wc;
  for (int idx = t; idx < Cc * Wc; idx += 256) {
    const int c = idx / Wc;
    const int ww = idx - c * Wc;
    const float v = __half2float(out_tile[c * TS + ww]);
    base[(size_t)c * HWc + ww] = (v - mstat[ww]) * rstat[ww] * gamma[c] + beta[c];
  }
}

// ---------------------------------------------------------------------------
extern "C" void kernel_launch(void* const* d_in, const int* in_sizes, int n_in,
                              void* d_out, int out_size, void* d_ws, size_t ws_size,
                              hipStream_t stream) {
  const float* x     = (const float*)d_in[0];
  const float* bias  = (const float*)d_in[1];
  const float* w     = (const float*)d_in[2];
  const float* cb    = (const float*)d_in[3];
  const float* mv1   = (const float*)d_in[4];
  const float* al    = (const float*)d_in[5];
  const float* mv2   = (const float*)d_in[6];
  const float* gamma = (const float*)d_in[7];
  const float* beta  = (const float*)d_in[8];
  float* out = (float*)d_out;

  uint8_t* ws = (uint8_t*)d_ws;
  uint32_t* zero_area = (uint32_t*)ws;
  const uint8_t* zb = ws;
  uint8_t* abytes = ws + ZBYTES;
  const size_t abytes_sz = (size_t)Bc * Gc * Hc * ROWBYTES;  // 16,515,072
  uint8_t* wbytes = abytes + abytes_sz;
  float* scales = (float*)(wbytes + (size_t)3 * Gc * 9 * 4096);

  hipLaunchKernelGGL(k_prep, dim3(192 + 1 + Bc * Hc * 2), dim3(256), 0, stream,
                     w, x, bias, wbytes, scales, abytes, zero_area);
  hipLaunchKernelGGL(k_conv_ln, dim3(Bc * Hc), dim3(256), 0, stream,
                     abytes, zb, wbytes, scales, cb, mv1, al, mv2, gamma, beta,
                     out);
}

// Round 10
// 500.382 us; speedup vs baseline: 1.0558x; 1.0558x over previous
//
#include <hip/hip_runtime.h>
#include <hip/hip_fp16.h>
#include <stdint.h>

static constexpr int Bc = 16, Cc = 256, Hc = 56, Wc = 56, Gc = 4;
static constexpr int HWc = Hc * Wc;
static constexpr float EPSc = 1e-5f;
static constexpr int ROWB = 72;          // padded w' positions per abytes row
static constexpr int COL0 = 8;           // [8 zero | 56 data | 8 zero]
static constexpr int ROWBYTES = ROWB * 64;  // 4608 B per (b,g,h) row
static constexpr int ZBYTES = 8192;      // zero row area (max read 4928 B)

typedef int i32x4 __attribute__((ext_vector_type(4)));

// ---------------------------------------------------------------------------
// Workspace:
//   ws + 0        : 8192 B zero area (zero "row"; conv reads <= 4928 B)
//   ws + 8192     : abytes [16][4][56][72][64] i8 = 16,515,072 B
//                   (sign bytes +-1; w' pads are 0 -> zero-padding is exact)
//   ws + 16523264 : wbytes [3][4][9][64 o][64 ci] i8 = 442,368 B
//   ws + 16965632 : scales [768] f32
// Overflow note: A-frag reads may run <=320 B past a row's end; they land in
// the next row's leading zero pad (512 B) or, for the very last row, in
// wbytes (allocated; affects only w>=56 garbage lanes, never stored).
// ---------------------------------------------------------------------------

static constexpr int SBS2 = 132;  // sign-byte LDS row stride (128 ch + pad)

__global__ __launch_bounds__(256) void k_prep(
    const float* __restrict__ w, const float* __restrict__ x,
    const float* __restrict__ bias, uint8_t* __restrict__ wbytes,
    float* __restrict__ scales, uint8_t* __restrict__ abytes,
    uint32_t* __restrict__ zero_area) {
  const int t = threadIdx.x;
  if (blockIdx.x < 192) {
    // ---- weight pack: io = blockIdx*4 + wave; lane = ci ----
    const int io = blockIdx.x * 4 + (t >> 6);
    const int i = io >> 8, o = io & 255;
    const int lane = t & 63;
    const float* wp = w + (size_t)io * 576 + lane * 9;
    float v[9];
    float ssum = 0.f, sabs = 0.f;
#pragma unroll
    for (int k = 0; k < 9; ++k) {
      v[k] = wp[k];
      ssum += v[k];
      sabs += fabsf(v[k]);
    }
#pragma unroll
    for (int off = 32; off > 0; off >>= 1) {
      ssum += __shfl_down(ssum, off);
      sabs += __shfl_down(sabs, off);
    }
    const float mean = __shfl(ssum, 0) * (1.f / 576.f);
    const float scale = __shfl(sabs, 0) * (1.f / 576.f);
    const int g = o >> 6, ol = o & 63;
    uint8_t* dst = wbytes + ((size_t)(i * 4 + g) * 9) * 4096 + ol * 64 + lane;
#pragma unroll
    for (int k = 0; k < 9; ++k)
      dst[k * 4096] = (v[k] > mean) ? (uint8_t)1 : (uint8_t)0xFF;
    if (lane == 0) scales[io] = scale;
  } else if (blockIdx.x == 192) {
    // zero area: 512 x 16 B = 8192 B
    uint4 z;
    z.x = z.y = z.z = z.w = 0u;
    ((uint4*)zero_area)[t] = z;
    ((uint4*)zero_area)[t + 256] = z;
  } else {
    // ---- activation pack: block = (b, h, channel-half). Coalesced float4
    // loads + LDS byte transpose; emit +-1 bytes [w'][ci] (u32 copies).
    __shared__ uint8_t sb[Wc * SBS2];  // [w][c_local], 7392 B
    const int bid = blockIdx.x - 193;
    const int b = bid / 112;
    const int rem = bid - b * 112;
    const int h = rem >> 1, chh = rem & 1;  // chh: channels [chh*128, +128)
    const float* xb = x + ((size_t)(b * Cc + chh * 128)) * HWc + h * Wc;
#pragma unroll
    for (int k = 0; k < 7; ++k) {
      const int idx = k * 256 + t;  // [0, 1792) = 128 c x 14 q
      const int cl = idx / 14, q = idx - cl * 14;
      const float4 v = *(const float4*)(xb + (size_t)cl * HWc + q * 4);
      const float bc = bias[chh * 128 + cl];
      sb[(q * 4 + 0) * SBS2 + cl] = (v.x + bc > 0.f) ? 1 : 0xFF;
      sb[(q * 4 + 1) * SBS2 + cl] = (v.y + bc > 0.f) ? 1 : 0xFF;
      sb[(q * 4 + 2) * SBS2 + cl] = (v.z + bc > 0.f) ? 1 : 0xFF;
      sb[(q * 4 + 3) * SBS2 + cl] = (v.w + bc > 0.f) ? 1 : 0xFF;
    }
    __syncthreads();
    // emit: 2 local groups x 72 w' x 16 dwords = 2304 u32 (9 iters)
    for (int idx = t; idx < 2 * ROWB * 16; idx += 256) {
      const int gl = idx / (ROWB * 16);
      const int r = idx - gl * (ROWB * 16);
      const int wp_ = r >> 4, d4 = r & 15;
      uint32_t word = 0;
      if (wp_ >= COL0 && wp_ < COL0 + Wc)
        word = *(const uint32_t*)(sb + (wp_ - COL0) * SBS2 + gl * 64 + d4 * 4);
      const int g = chh * 2 + gl;
      *(uint32_t*)(abytes + ((size_t)((b * Gc + g) * Hc + h)) * ROWBYTES +
                   wp_ * 64 + d4 * 4) = word;
    }
  }
}

// ---------------------------------------------------------------------------
// One branch for one 16-row M-pass, 16x16x64 i8 MFMA (layouts HW-verified in
// r9: A lane l -> row l&15, K-chunk (l>>4)*16, contiguous 1 KB/frag; D col =
// lane&15 = o, row = (lane>>4)*4 + q). Register-minimal: one A in flight,
// B streamed per (tap,n), params re-loaded per pass (L1-hot) — keeps live
// state ~85 regs, under the 128 the allocator grants (r5-r9 lesson).
// ---------------------------------------------------------------------------
template <int D>
__device__ __forceinline__ void conv_branch16(
    const uint8_t* __restrict__ r0, const uint8_t* __restrict__ r1,
    const uint8_t* __restrict__ r2, const uint8_t* __restrict__ wb,
    int w0, int lr, int kc, const float* __restrict__ scp,
    const float* __restrict__ cbp, const float* __restrict__ m1p,
    const float* __restrict__ alp, int o0, float (&outf)[4][4]) {
  i32x4 acc[4];
#pragma unroll
  for (int n = 0; n < 4; ++n) acc[n] = i32x4{0, 0, 0, 0};
#pragma unroll
  for (int tap = 0; tap < 9; ++tap) {
    const uint8_t* r = (tap < 3) ? r0 : ((tap < 6) ? r1 : r2);
    const int kw = tap % 3 - 1;
    const i32x4 A =
        *(const i32x4*)(r + (COL0 + w0 + D * kw + lr) * 64 + kc);
#pragma unroll
    for (int n = 0; n < 4; ++n) {
      const i32x4 Bf =
          *(const i32x4*)(wb + tap * 4096 + n * 1024 + lr * 64 + kc);
      acc[n] = __builtin_amdgcn_mfma_i32_16x16x64_i8(A, Bf, acc[n], 0, 0, 0);
    }
  }
#pragma unroll
  for (int n = 0; n < 4; ++n) {
    const int o = o0 + n * 16;
    const float sc = scp[o];
    const float cc = cbp[o] - m1p[o];
    const float aa = alp[o];
#pragma unroll
    for (int q = 0; q < 4; ++q) {
      const float y = fmaf(sc, (float)acc[n][q], cc);
      outf[n][q] += fmaxf(y, 0.f) + aa * fminf(y, 0.f);
    }
  }
}

// ---------------------------------------------------------------------------
// K2: fused conv(3 branches, 16x16x64 i8 MFMA)+bias+RPReLU+sum+LayerNorm.
// Block = (b,h) full row; wave = group g; 4 sequential 16-row M-passes.
// XCD-chunked bijective swizzle (896 = 8*112) keeps each XCD's abytes slice
// L2-resident (r8: FETCH 11 MB).
// ---------------------------------------------------------------------------
static constexpr int TS = 60;  // out_tile stride (halfs)

__global__ __launch_bounds__(256, 2) void k_conv_ln(
    const uint8_t* __restrict__ abytes, const uint8_t* __restrict__ zb,
    const uint8_t* __restrict__ wbytes, const float* __restrict__ scales,
    const float* __restrict__ cb, const float* __restrict__ mv1,
    const float* __restrict__ al, const float* __restrict__ mv2,
    const float* __restrict__ gamma, const float* __restrict__ beta,
    float* __restrict__ out) {
  __shared__ __half out_tile[Cc * TS];
  __shared__ float redu[4][Wc], redq[4][Wc];
  __shared__ float mstat[Wc], rstat[Wc];

  const int bid0 = blockIdx.x;                     // hw id (round-robin XCD)
  const int bid = (bid0 & 7) * 112 + (bid0 >> 3);  // b*56 + h, XCD-chunked
  const int b = bid / Hc, h = bid % Hc;
  const int t = threadIdx.x;
  const int gu = __builtin_amdgcn_readfirstlane(t >> 6);  // group
  const int lane = t & 63;
  const int lr = lane & 15;         // row (w) / col (o) within 16-tile
  const int kc = (lane >> 4) * 16;  // K-chunk byte offset
  const int o0 = gu * 64 + lr;      // base output channel for n-tiles

  const uint8_t* ab_g = abytes + (size_t)((b * Gc + gu) * Hc) * ROWBYTES;
  const uint8_t* r1m = (h - 1 >= 0) ? ab_g + (size_t)(h - 1) * ROWBYTES : zb;
  const uint8_t* rmd = ab_g + (size_t)h * ROWBYTES;
  const uint8_t* r1p = (h + 1 < Hc) ? ab_g + (size_t)(h + 1) * ROWBYTES : zb;
  const uint8_t* r3m = (h - 3 >= 0) ? ab_g + (size_t)(h - 3) * ROWBYTES : zb;
  const uint8_t* r3p = (h + 3 < Hc) ? ab_g + (size_t)(h + 3) * ROWBYTES : zb;
  const uint8_t* r5m = (h - 5 >= 0) ? ab_g + (size_t)(h - 5) * ROWBYTES : zb;
  const uint8_t* r5p = (h + 5 < Hc) ? ab_g + (size_t)(h + 5) * ROWBYTES : zb;

  const uint8_t* wb0 = wbytes + (size_t)(0 * Gc + gu) * 9 * 4096;
  const uint8_t* wb1 = wbytes + (size_t)(1 * Gc + gu) * 9 * 4096;
  const uint8_t* wb2 = wbytes + (size_t)(2 * Gc + gu) * 9 * 4096;

#pragma unroll 1
  for (int m0p = 0; m0p < 4; ++m0p) {  // 16-row M-pass (rows w0..w0+15)
    const int w0 = m0p * 16;
    float outf[4][4];  // [n][q], static-indexed
#pragma unroll
    for (int n = 0; n < 4; ++n) {
      const int o = o0 + n * 16;
      const float m2 = mv2[o] + mv2[256 + o] + mv2[512 + o];
#pragma unroll
      for (int q = 0; q < 4; ++q) outf[n][q] = m2;
    }

    conv_branch16<1>(r1m, rmd, r1p, wb0, w0, lr, kc, scales, cb, mv1, al, o0,
                     outf);
    conv_branch16<3>(r3m, rmd, r3p, wb1, w0, lr, kc, scales + 256, cb + 256,
                     mv1 + 256, al + 256, o0, outf);
    conv_branch16<5>(r5m, rmd, r5p, wb2, w0, lr, kc, scales + 512, cb + 512,
                     mv1 + 512, al + 512, o0, outf);

    // store: o = o0 + n*16 (col), w = w0 + (lane>>4)*4 + q (row)
    const int wbase = w0 + (lane >> 4) * 4;
#pragma unroll
    for (int n = 0; n < 4; ++n) {
      const int o = o0 + n * 16;
#pragma unroll
      for (int q = 0; q < 4; ++q) {
        const int wl = wbase + q;
        if (wl < Wc) out_tile[o * TS + wl] = __float2half(outf[n][q]);
      }
    }
  }
  __syncthreads();

  // ---- LN stats (per output column over 256 channels) ----
  if (t < 4 * Wc) {
    const int ww = t % Wc;
    const int cq = t / Wc;
    float s = 0.f, sq = 0.f;
#pragma unroll 4
    for (int c = cq * 64; c < cq * 64 + 64; ++c) {
      const float v = __half2float(out_tile[c * TS + ww]);
      s += v;
      sq = fmaf(v, v, sq);
    }
    redu[cq][ww] = s;
    redq[cq][ww] = sq;
  }
  __syncthreads();
  if (t < Wc) {
    const float s = redu[0][t] + redu[1][t] + redu[2][t] + redu[3][t];
    const float sq = redq[0][t] + redq[1][t] + redq[2][t] + redq[3][t];
    const float mean = s * (1.f / 256.f);
    const float var = sq * (1.f / 256.f) - mean * mean;
    mstat[t] = mean;
    rstat[t] = rsqrtf(var + EPSc);
  }
  __syncthreads();

  // ---- normalize + coalesced store ----
  float* base = out + ((size_t)b * Cc * Hc + h) * Wc;
  for (int idx = t; idx < Cc * Wc; idx += 256) {
    const int c = idx / Wc;
    const int ww = idx - c * Wc;
    const float v = __half2float(out_tile[c * TS + ww]);
    base[(size_t)c * HWc + ww] = (v - mstat[ww]) * rstat[ww] * gamma[c] + beta[c];
  }
}

// ---------------------------------------------------------------------------
extern "C" void kernel_launch(void* const* d_in, const int* in_sizes, int n_in,
                              void* d_out, int out_size, void* d_ws, size_t ws_size,
                              hipStream_t stream) {
  const float* x     = (const float*)d_in[0];
  const float* bias  = (const float*)d_in[1];
  const float* w     = (const float*)d_in[2];
  const float* cb    = (const float*)d_in[3];
  const float* mv1   = (const float*)d_in[4];
  const float* al    = (const float*)d_in[5];
  const float* mv2   = (const float*)d_in[6];
  const float* gamma = (const float*)d_in[7];
  const float* beta  = (const float*)d_in[8];
  float* out = (float*)d_out;

  uint8_t* ws = (uint8_t*)d_ws;
  uint32_t* zero_area = (uint32_t*)ws;
  const uint8_t* zb = ws;
  uint8_t* abytes = ws + ZBYTES;
  const size_t abytes_sz = (size_t)Bc * Gc * Hc * ROWBYTES;  // 16,515,072
  uint8_t* wbytes = abytes + abytes_sz;
  float* scales = (float*)(wbytes + (size_t)3 * Gc * 9 * 4096);

  hipLaunchKernelGGL(k_prep, dim3(192 + 1 + Bc * Hc * 2), dim3(256), 0, stream,
                     w, x, bias, wbytes, scales, abytes, zero_area);
  hipLaunchKernelGGL(k_conv_ln, dim3(Bc * Hc), dim3(256), 0, stream,
                     abytes, zb, wbytes, scales, cb, mv1, al, mv2, gamma, beta,
                     out);
}

// Round 11
// 176.233 us; speedup vs baseline: 2.9979x; 2.8393x over previous
//
#include <hip/hip_runtime.h>
#include <hip/hip_fp16.h>
#include <stdint.h>

static constexpr int Bc = 16, Cc = 256, Hc = 56, Wc = 56, Gc = 4;
static constexpr int HWc = Hc * Wc;
static constexpr float EPSc = 1e-5f;
static constexpr int ROWP = 72;   // padded abits row: [8 zero | 56 data | 8 zero]
static constexpr int COL0 = 8;

// ---------------------------------------------------------------------------
// Workspace (r4 layout):
//   ws + 0       : 1024 B zero area (zrowp = ws + 8 u64)
//   ws + 1024    : abits_pad [16][4][56][72] u64 = 2,064,384 B
//   ws + 2065408 : wbits [3][9][256] u64 = 55,296 B
//   ws + 2120704 : scales [768] f32
// ---------------------------------------------------------------------------

static constexpr int SBS2 = 132;  // sign-byte LDS row stride (128 ch + pad)

__global__ __launch_bounds__(256) void k_prep(
    const float* __restrict__ w, const float* __restrict__ x,
    const float* __restrict__ bias, uint64_t* __restrict__ wbits,
    float* __restrict__ scales, uint64_t* __restrict__ abits,
    uint32_t* __restrict__ zero_area) {
  const int t = threadIdx.x;
  if (blockIdx.x < 192) {
    // ---- weight pack: io = blockIdx*4 + wave ----
    const int io = blockIdx.x * 4 + (t >> 6);
    const int i = io >> 8, o = io & 255;
    const int lane = t & 63;
    const float* wp = w + (size_t)io * 576 + lane * 9;
    float v[9];
    float ssum = 0.f, sabs = 0.f;
#pragma unroll
    for (int k = 0; k < 9; ++k) {
      v[k] = wp[k];
      ssum += v[k];
      sabs += fabsf(v[k]);
    }
#pragma unroll
    for (int off = 32; off > 0; off >>= 1) {
      ssum += __shfl_down(ssum, off);
      sabs += __shfl_down(sabs, off);
    }
    const float mean = __shfl(ssum, 0) * (1.f / 576.f);
    const float scale = __shfl(sabs, 0) * (1.f / 576.f);
#pragma unroll
    for (int k = 0; k < 9; ++k) {
      unsigned long long m = __ballot(v[k] > mean);
      if (lane == 0) wbits[(i * 9 + k) * Cc + o] = m;
    }
    if (lane == 0) scales[io] = scale;
  } else if (blockIdx.x == 192) {
    zero_area[t] = 0;  // 1024 B
  } else {
    // ---- activation pack: block = (b, h, channel-half). 1792 blocks.
    // Coalesced float4 loads + LDS byte transpose + nibble bit-pack.
    __shared__ uint8_t sb[Wc * SBS2];  // [w][c_local], 7392 B
    const int bid = blockIdx.x - 193;
    const int b = bid / 112;
    const int rem = bid - b * 112;
    const int h = rem >> 1, chh = rem & 1;  // chh: channels [chh*128, +128)
    const float* xb = x + ((size_t)(b * Cc + chh * 128)) * HWc + h * Wc;
#pragma unroll
    for (int k = 0; k < 7; ++k) {
      const int idx = k * 256 + t;  // [0, 1792) = 128 c x 14 q
      const int cl = idx / 14, q = idx - cl * 14;
      const float4 v = *(const float4*)(xb + (size_t)cl * HWc + q * 4);
      const float bc = bias[chh * 128 + cl];
      sb[(q * 4 + 0) * SBS2 + cl] = (v.x + bc > 0.f);
      sb[(q * 4 + 1) * SBS2 + cl] = (v.y + bc > 0.f);
      sb[(q * 4 + 2) * SBS2 + cl] = (v.z + bc > 0.f);
      sb[(q * 4 + 3) * SBS2 + cl] = (v.w + bc > 0.f);
    }
    __syncthreads();
    // pack: 2 local groups x 72 padded words
    if (t < 2 * ROWP) {
      const int gl = t / ROWP, k = t - gl * ROWP;
      uint64_t word = 0;
      if (k >= COL0 && k < COL0 + Wc) {
        const int ww = k - COL0;
        const uint32_t* p = (const uint32_t*)(sb + ww * SBS2 + gl * 64);
        uint64_t acc = 0;
#pragma unroll
        for (int dw = 0; dw < 16; ++dw) {
          const uint32_t d = p[dw];
          const uint32_t nib = (d | (d >> 7) | (d >> 14) | (d >> 21)) & 0xF;
          acc |= (uint64_t)nib << (4 * dw);
        }
        word = acc;
      }
      const int g = chh * 2 + gl;
      abits[(((size_t)b * Gc + g) * Hc + h) * ROWP + k] = word;
    }
  }
}

// ---------------------------------------------------------------------------
// Per-branch conv state (r4-proven popcount scheme). Row pointers wave-
// uniform; segments -> SGPRs. Row h (kh=1) SHARED across branches via
// smid[17]. Exact integer correction:
//   B(w) = 576 - Zrow - (w<D)?ZL:0 - (w>=56-D)?ZR:0;  dot = B - 2*sum popc
// ---------------------------------------------------------------------------
static constexpr int NCH = 7;   // chunk width
static constexpr int WH = 28;   // half-row width
static constexpr int TSH = 30;  // padded out_tile stride (halfs)

template <int D>
struct Branch {
  uint64_t wgt[9];
  const uint64_t *r0, *r2;  // kh=0 / kh=2 rows (col 0)
  int BM, ZL, ZR;
  float sc, cbm1, al;

  __device__ __forceinline__ void init(const uint64_t* __restrict__ wb,
                                       const uint64_t* rowbase,  // col0,row0
                                       const uint64_t* zrowp, int h,
                                       float sc_, float cbm1_, float al_) {
    sc = sc_; cbm1 = cbm1_; al = al_;
    int z[9];
#pragma unroll
    for (int k = 0; k < 9; ++k) {
      wgt[k] = wb[k * Cc];
      z[k] = 64 - 2 * (int)__builtin_popcountll(wgt[k]);
    }
    const bool v0 = (h - D >= 0), v2 = (h + D < Hc);
    r0 = v0 ? (rowbase + (size_t)(h - D) * ROWP) : zrowp;
    r2 = v2 ? (rowbase + (size_t)(h + D) * ROWP) : zrowp;
    const int Zrow = (v0 ? 0 : (z[0] + z[1] + z[2])) +
                     (v2 ? 0 : (z[6] + z[7] + z[8]));
    BM = 576 - Zrow;
    ZL = (v0 ? z[0] : 0) + z[3] + (v2 ? z[6] : 0);
    ZR = (v0 ? z[2] : 0) + z[5] + (v2 ? z[8] : 0);
  }

  // kh = 0, 2 rows
  __device__ __forceinline__ void accum_edge(int w0, int acc[NCH]) const {
#pragma unroll
    for (int kh = 0; kh < 3; kh += 2) {
      const uint64_t* rp = (kh == 0) ? r0 : r2;
      uint64_t seg[NCH + 2 * D];  // wave-uniform -> SGPRs
#pragma unroll
      for (int j = 0; j < NCH + 2 * D; ++j) seg[j] = rp[w0 - D + j];
#pragma unroll
      for (int ww = 0; ww < NCH; ++ww) {
#pragma unroll
        for (int kw = 0; kw < 3; ++kw)
          acc[ww] +=
              (int)__builtin_popcountll(wgt[kh * 3 + kw] ^ seg[ww + D * kw]);
      }
    }
  }

  // kh = 1 from shared row-h segment smid[j] = r1[w0 - 5 + j]
  __device__ __forceinline__ void accum_mid(const uint64_t* smid,
                                            int acc[NCH]) const {
#pragma unroll
    for (int ww = 0; ww < NCH; ++ww) {
#pragma unroll
      for (int kw = 0; kw < 3; ++kw)
        acc[ww] += (int)__builtin_popcountll(
            wgt[3 + kw] ^ smid[ww + 5 - D + D * kw]);
    }
  }

  // interior chunk: no W-edge corrections (B = BM for all outputs)
  __device__ __forceinline__ void epi_int(const int acc[NCH],
                                          float outf[NCH]) const {
#pragma unroll
    for (int ww = 0; ww < NCH; ++ww) {
      const float y0 = fmaf(sc, (float)(BM - 2 * acc[ww]), cbm1);
      outf[ww] += fmaxf(y0, 0.f) + al * fminf(y0, 0.f);
    }
  }

  __device__ __forceinline__ void epi_edge(int w0, const int acc[NCH],
                                           float outf[NCH]) const {
#pragma unroll
    for (int ww = 0; ww < NCH; ++ww) {
      const int w = w0 + ww;
      const int B = BM - ((w < D) ? ZL : 0) - ((w >= Wc - D) ? ZR : 0);
      const float y0 = fmaf(sc, (float)(B - 2 * acc[ww]), cbm1);
      outf[ww] += fmaxf(y0, 0.f) + al * fminf(y0, 0.f);
    }
  }
};

// ---------------------------------------------------------------------------
// K2: fused conv(3 branches)+bias+RPReLU+sum+LayerNorm. Block = (b,h,half):
// 28 output columns x 256 channels. Thread = output channel.
// XCD-chunked bijective swizzle (1792 = 8*224): each XCD owns 224 consecutive
// half-row blocks = 2 images of abits slice -> L2-resident (r8-proven).
// ---------------------------------------------------------------------------
__global__ __launch_bounds__(256, 4) void k_conv_ln(
    const uint64_t* __restrict__ abits, const uint64_t* __restrict__ zrowp,
    const uint64_t* __restrict__ wbits, const float* __restrict__ scales,
    const float* __restrict__ cb, const float* __restrict__ mv1,
    const float* __restrict__ al, const float* __restrict__ mv2,
    const float* __restrict__ gamma, const float* __restrict__ beta,
    float* __restrict__ out) {
  __shared__ __half out_tile[Cc * TSH];
  __shared__ float redu[4][WH], redq[4][WH];
  __shared__ float mstat[WH], rstat[WH];

  const int bid0 = blockIdx.x;                     // hw id (round-robin XCD)
  const int swz = (bid0 & 7) * 224 + (bid0 >> 3);  // XCD-chunked, bijective
  const int wh = swz & 1;   // which half of the row
  const int bh = swz >> 1;  // b*56 + h
  const int b = bh / Hc, h = bh % Hc;
  const int W0 = wh * WH;
  const int t = threadIdx.x;  // output channel
  const int gu = __builtin_amdgcn_readfirstlane(t >> 6);

  const uint64_t* rowbase = abits + ((size_t)b * Gc + gu) * Hc * ROWP + COL0;
  const uint64_t* r1 = rowbase + (size_t)h * ROWP;  // mid row, always valid

  Branch<1> b0; Branch<3> b1; Branch<5> b2;
  b0.init(wbits + 0 * 9 * Cc + t, rowbase, zrowp, h, scales[0 * Cc + t],
          cb[0 * Cc + t] - mv1[0 * Cc + t], al[0 * Cc + t]);
  b1.init(wbits + 1 * 9 * Cc + t, rowbase, zrowp, h, scales[1 * Cc + t],
          cb[1 * Cc + t] - mv1[1 * Cc + t], al[1 * Cc + t]);
  b2.init(wbits + 2 * 9 * Cc + t, rowbase, zrowp, h, scales[2 * Cc + t],
          cb[2 * Cc + t] - mv1[2 * Cc + t], al[2 * Cc + t]);
  const float m2sum = mv2[0 * Cc + t] + mv2[1 * Cc + t] + mv2[2 * Cc + t];

#pragma unroll 1
  for (int ch = 0; ch < 4; ++ch) {  // runtime loop: keeps live ranges small
    const int w0 = W0 + ch * NCH;
    // shared row-h segment, span [w0-5, w0+12): covers kh=1 of all branches
    uint64_t smid[17];
#pragma unroll
    for (int j = 0; j < 17; ++j) smid[j] = r1[w0 - 5 + j];
    const bool interior = (w0 >= 5) && (w0 <= Wc - NCH - 5);  // all B == BM
    float outf[NCH];
#pragma unroll
    for (int ww = 0; ww < NCH; ++ww) outf[ww] = m2sum;
    {
      int acc[NCH] = {};
      b0.accum_edge(w0, acc); b0.accum_mid(smid, acc);
      if (interior) b0.epi_int(acc, outf); else b0.epi_edge(w0, acc, outf);
    }
    {
      int acc[NCH] = {};
      b1.accum_edge(w0, acc); b1.accum_mid(smid, acc);
      if (interior) b1.epi_int(acc, outf); else b1.epi_edge(w0, acc, outf);
    }
    {
      int acc[NCH] = {};
      b2.accum_edge(w0, acc); b2.accum_mid(smid, acc);
      if (interior) b2.epi_int(acc, outf); else b2.epi_edge(w0, acc, outf);
    }
#pragma unroll
    for (int ww = 0; ww < NCH; ++ww)
      out_tile[t * TSH + ch * NCH + ww] = __float2half(outf[ww]);
  }
  __syncthreads();

  // ---- LN stats (per output column over 256 channels) ----
  if (t < 4 * WH) {
    const int ww = t % WH;
    const int cq = t / WH;
    float s = 0.f, sq = 0.f;
#pragma unroll 4
    for (int c = cq * 64; c < cq * 64 + 64; ++c) {
      const float v = __half2float(out_tile[c * TSH + ww]);
      s += v;
      sq = fmaf(v, v, sq);
    }
    redu[cq][ww] = s;
    redq[cq][ww] = sq;
  }
  __syncthreads();
  if (t < WH) {
    const float s = redu[0][t] + redu[1][t] + redu[2][t] + redu[3][t];
    const float sq = redq[0][t] + redq[1][t] + redq[2][t] + redq[3][t];
    const float mean = s * (1.f / 256.f);
    const float var = sq * (1.f / 256.f) - mean * mean;
    mstat[t] = mean;
    rstat[t] = rsqrtf(var + EPSc);
  }
  __syncthreads();

  // ---- normalize + coalesced store ----
  float* base = out + ((size_t)b * Cc * Hc + h) * Wc + W0;
  for (int idx = t; idx < Cc * WH; idx += 256) {
    const int c = idx / WH;
    const int ww = idx - c * WH;
    const float v = __half2float(out_tile[c * TSH + ww]);
    base[(size_t)c * HWc + ww] = (v - mstat[ww]) * rstat[ww] * gamma[c] + beta[c];
  }
}

// ---------------------------------------------------------------------------
extern "C" void kernel_launch(void* const* d_in, const int* in_sizes, int n_in,
                              void* d_out, int out_size, void* d_ws, size_t ws_size,
                              hipStream_t stream) {
  const float* x     = (const float*)d_in[0];
  const float* bias  = (const float*)d_in[1];
  const float* w     = (const float*)d_in[2];
  const float* cb    = (const float*)d_in[3];
  const float* mv1   = (const float*)d_in[4];
  const float* al    = (const float*)d_in[5];
  const float* mv2   = (const float*)d_in[6];
  const float* gamma = (const float*)d_in[7];
  const float* beta  = (const float*)d_in[8];
  float* out = (float*)d_out;

  uint8_t* ws = (uint8_t*)d_ws;
  uint32_t* zero_area = (uint32_t*)ws;
  const uint64_t* zrowp = (const uint64_t*)ws + COL0;
  uint64_t* abits = (uint64_t*)(ws + 1024);
  const size_t abits_bytes = (size_t)Bc * Gc * Hc * ROWP * 8;  // 2,064,384
  uint64_t* wbits = (uint64_t*)(ws + 1024 + abits_bytes);
  float* scales = (float*)(ws + 1024 + abits_bytes + 6912 * 8);

  hipLaunchKernelGGL(k_prep, dim3(192 + 1 + Bc * Hc * 2), dim3(256), 0, stream,
                     w, x, bias, wbits, scales, abits, zero_area);
  hipLaunchKernelGGL(k_conv_ln, dim3(Bc * Hc * 2), dim3(256), 0, stream,
                     abits, zrowp, wbits, scales, cb, mv1, al, mv2, gamma, beta,
                     out);
}